// Round 3
// baseline (88.583 us; speedup 1.0000x reference)
//
#include <hip/hip_runtime.h>
#include <math.h>

// Problem constants (fixed by setup_inputs): N src points, M targets, D=3.
constexpr int N_SRC = 16384;
constexpr int M_TAR = 16384;

// R8: R7 structure unchanged; ONLY the register cap is fixed.
// R7 evidence: VGPR_Count=60 (64-reg tier!) while live state is ~100 regs ->
// ~40 values lived in AGPR/scratch, and VALU issue time measured 30.8us =
// 2.0x the 15.4us instruction-exact floor (register-shuffle ops doubled the
// instruction stream). __launch_bounds__(512, 4) compiled to the 8-waves/
// SIMD (<=64 VGPR) tier; (512, 2) raises the cap to >=128 under either
// semantics of the 2nd arg. Occupancy is unchanged: LDS 64KB already caps
// residency at 2 blocks/CU = 16 waves/CU = 4 waves/SIMD, which hardware
// permits at <=128 VGPRs. Inner loop remains instruction-exact:
//   per pair: 3 v_fma_f32 + 1 v_and_or_b32 + 0.5 v_min3_f32 = 4.5 VALU ops
// with TPT=16 targets/thread (LDS reads = M*N/TPT).
constexpr int BLOCKS = 512;            // 32 targets per block
constexpr int TPB = 512;               // 8 waves
constexpr int CHUNKS = 256;            // chunk = tid & 255
constexpr int TILE = 2048;             // sources per LDS tile (32 KB float4)
constexpr int TILES = N_SRC / TILE;    // 8
constexpr int ROWS_PT = TILE / CHUNKS; // 8 rows per tile
constexpr int IPT = ROWS_PT / 2;       // 4 source-pairs per tile per thread
constexpr int TPT = 16;                // targets per thread
constexpr int PPT = TILE / TPB;        // 4 staged points per thread per tile

__global__ void zero_out(float* __restrict__ out) {
    if (threadIdx.x == 0) out[0] = 0.0f;  // d_out poisoned 0xAA each launch
}

// (t & mask_v) | row_s  — mask forced to VGPR, uniform row rides the SGPR slot
__device__ __forceinline__ float embed_ao(float t, unsigned mask_v, unsigned row_s) {
    float r;
    asm("v_and_or_b32 %0, %1, %2, %3"
        : "=v"(r) : "v"(t), "v"(mask_v), "s"(row_s));
    return r;
}
// best = min(best, e0, e1) in one instruction (inputs never NaN here)
__device__ __forceinline__ void min3(float& b, float e0, float e1) {
    asm("v_min3_f32 %0, %0, %1, %2"
        : "+v"(b) : "v"(e0), "v"(e1));
}

// 2nd arg = 2: under CUDA/blocks semantics -> 2 blocks/CU -> cap 128 VGPR;
// under waves-per-EU semantics -> cap 256. Either way the ~100-reg live set
// stays in arch VGPRs. (R7's "4" compiled to the 64-VGPR tier: VGPR_Count=60.)
__global__ __launch_bounds__(TPB, 2) void nn9(const float* __restrict__ src,
                                              const float* __restrict__ tar,
                                              float* __restrict__ out) {
    __shared__ float4 tile[2 * TILE];  // 64 KB double buffer; reused in tail

    const int tid   = threadIdx.x;
    const int g     = tid >> 8;     // 0..1: target half owned by this thread
    const int chunk = tid & 255;    // 0..255: source slice
    const int tbase = blockIdx.x * 32;

    // 16 targets/thread, premultiplied by -2 so ||s||^2 folds into the fmas
    float txm2[TPT], tym2[TPT], tzm2[TPT], best[TPT];
#pragma unroll
    for (int k = 0; k < TPT; ++k) {
        int T = tbase + g * TPT + k;
        txm2[k] = -2.0f * tar[3 * T + 0];
        tym2[k] = -2.0f * tar[3 * T + 1];
        tzm2[k] = -2.0f * tar[3 * T + 2];
        best[k] = INFINITY;
    }

    // ---- prolog: stage tile 0
#pragma unroll
    for (int r = 0; r < PPT; ++r) {
        int p = tid + r * TPB;
        const float* q = src + 3 * p;
        float x = q[0], y = q[1], z = q[2];
        tile[p] = make_float4(x, y, z, fmaf(x, x, fmaf(y, y, z * z)));
    }
    __syncthreads();

    unsigned mask_v = 0xFFFFFFC0u;  // lives in a VGPR for v_and_or_b32

    auto compute = [&](int cb, unsigned rowbase) {
#pragma unroll
        for (int i = 0; i < IPT; ++i) {
            float4 s0 = tile[cb + (2 * i + 0) * CHUNKS + chunk];
            float4 s1 = tile[cb + (2 * i + 1) * CHUNKS + chunk];
            unsigned row0 = rowbase + 2 * i;      // uniform (SGPR)
            unsigned row1 = rowbase + 2 * i + 1;  // uniform (SGPR)
#pragma unroll
            for (int k = 0; k < TPT; ++k) {
                float t0 = fmaf(s0.z, tzm2[k], s0.w);
                t0 = fmaf(s0.y, tym2[k], t0);
                t0 = fmaf(s0.x, txm2[k], t0);
                float t1 = fmaf(s1.z, tzm2[k], s1.w);
                t1 = fmaf(s1.y, tym2[k], t1);
                t1 = fmaf(s1.x, txm2[k], t1);
                float e0 = embed_ao(t0, mask_v, row0);
                float e1 = embed_ao(t1, mask_v, row1);
                min3(best[k], e0, e1);
            }
        }
    };

    // ---- pipelined main loop: prefetch tl+1, compute tl, write tl+1
#pragma unroll 1
    for (int tl = 0; tl < TILES - 1; ++tl) {
        float px[PPT], py[PPT], pz[PPT];
#pragma unroll
        for (int r = 0; r < PPT; ++r) {
            const float* q = src + 3 * ((tl + 1) * TILE + tid + r * TPB);
            px[r] = q[0]; py[r] = q[1]; pz[r] = q[2];
        }
        __builtin_amdgcn_sched_barrier(0);  // keep load issues above compute

        compute((tl & 1) * TILE, (unsigned)(tl * ROWS_PT));

        const int wb = ((tl + 1) & 1) * TILE;
#pragma unroll
        for (int r = 0; r < PPT; ++r) {
            float x = px[r], y = py[r], z = pz[r];
            tile[wb + tid + r * TPB] =
                make_float4(x, y, z, fmaf(x, x, fmaf(y, y, z * z)));
        }
        __syncthreads();  // publishes writes for tl+1; retires reads of tl
    }
    compute(((TILES - 1) & 1) * TILE, (unsigned)((TILES - 1) * ROWS_PT));

    // ---- tail: resolve indices, merge 256 chunks per target, loss, atomic
    __syncthreads();                     // all compute reads of tile done
    float* fv = (float*)tile;            // [32][256] values  (32 KB)
    int*   fj = (int*)tile + 32 * 256;   // [32][256] indices (32 KB)
#pragma unroll
    for (int k = 0; k < TPT; ++k) {
        unsigned b = __float_as_uint(best[k]);
        int j  = (int)((b & 63u) * CHUNKS + chunk);  // j = row*256 + chunk
        int lt = g * TPT + k;
        fv[lt * CHUNKS + chunk] = __uint_as_float(b & 0xFFFFFFC0u);
        fj[lt * CHUNKS + chunk] = j;
    }
    __syncthreads();

    const int tprime = tid >> 4;   // 0..31: target this 16-lane group reduces
    const int sub    = tid & 15;
    float bv = fv[tprime * CHUNKS + sub];
    int   bj = fj[tprime * CHUNKS + sub];
#pragma unroll
    for (int m = 1; m < CHUNKS / 16; ++m) {
        float v = fv[tprime * CHUNKS + sub + 16 * m];
        int   j = fj[tprime * CHUNKS + sub + 16 * m];
        if (v < bv) { bv = v; bj = j; }
    }
#pragma unroll
    for (int s = 8; s >= 1; s >>= 1) {   // xor<16 stays in the 16-lane group
        float vv = __shfl_xor(bv, s, 64);
        int   jj = __shfl_xor(bj, s, 64);
        if (vv < bv) { bv = vv; bj = jj; }
    }
    __syncthreads();  // done reading fv/fj; safe to reuse

    if (sub == 0) {
        int tt = tbase + tprime;
        // exact loss term from the winning index (reference formula)
        float dx = src[3 * bj + 0] - tar[3 * tt + 0];
        float dy = src[3 * bj + 1] - tar[3 * tt + 1];
        float dz = src[3 * bj + 2] - tar[3 * tt + 2];
        fv[tprime] = 0.5f * fmaf(dx, dx, fmaf(dy, dy, dz * dz));
    }
    __syncthreads();
    if (tid == 0) {
        float ssum = 0.0f;
#pragma unroll
        for (int i = 0; i < 32; ++i) ssum += fv[i];
        atomicAdd(out, ssum);  // device-scope, cross-XCD safe
    }
}

extern "C" void kernel_launch(void* const* d_in, const int* in_sizes, int n_in,
                              void* d_out, int out_size, void* d_ws, size_t ws_size,
                              hipStream_t stream) {
    const float* src = (const float*)d_in[0];  // src_V [N,3] fp32
    const float* tar = (const float*)d_in[1];  // tar_V [M,3] fp32
    float* out = (float*)d_out;                // scalar loss fp32
    (void)d_ws; (void)ws_size;

    zero_out<<<1, 64, 0, stream>>>(out);
    nn9<<<BLOCKS, TPB, 0, stream>>>(src, tar, out);
}

// Round 4
// 85.573 us; speedup vs baseline: 1.0352x; 1.0352x over previous
//
#include <hip/hip_runtime.h>
#include <math.h>

// Problem constants (fixed by setup_inputs): N src points, M targets, D=3.
constexpr int N_SRC = 16384;
constexpr int M_TAR = 16384;

// R9: two changes vs R8, both aimed at the measured 2x VALU-issue excess
// (30us busy vs 15.4us instruction floor; VGPR_Count stuck at 60 across two
// launch_bounds settings = allocator parking ~35 live values in AGPRs and
// paying v_accvgpr shuffles on every coefficient access):
//  (1) amdgpu_waves_per_eu(4,4): LDS (64KB) already caps occupancy at
//      2 blocks/CU = 4 waves/SIMD; pinning min=max=4 gives the allocator a
//      128-VGPR budget with nothing to gain from staying under 64.
//  (2) value-only scan: per pair-of-sources 6 v_fma_f32 + 1 v_min3_f32 =
//      3.5 VALU ops/pair (was 4.5 with index-embedding). Index recovery in
//      the tail: per target, reduce (value, chunk) over the 256 chunks, then
//      the 16-lane group rescans the winning chunk's 64 rows from L2-resident
//      src with the BIT-IDENTICAL fma chain and matches v==best (exact by
//      construction). Ties across chunks give equal d^2 -> equal loss.
constexpr int BLOCKS = 512;            // 32 targets per block
constexpr int TPB = 512;               // 8 waves
constexpr int CHUNKS = 256;            // chunk = tid & 255
constexpr int TILE = 2048;             // sources per LDS tile (32 KB float4)
constexpr int TILES = N_SRC / TILE;    // 8
constexpr int ROWS_PT = TILE / CHUNKS; // 8 rows per tile
constexpr int IPT = ROWS_PT / 2;       // 4 source-pairs per tile per thread
constexpr int TPT = 16;                // targets per thread
constexpr int PPT = TILE / TPB;        // 4 staged points per thread per tile
constexpr int NROWS = N_SRC / CHUNKS;  // 64 rows per chunk overall

__global__ void zero_out(float* __restrict__ out) {
    if (threadIdx.x == 0) out[0] = 0.0f;  // d_out poisoned 0xAA each launch
}

// best = min(best, e0, e1) in one instruction (inputs never NaN here)
__device__ __forceinline__ void min3(float& b, float e0, float e1) {
    asm("v_min3_f32 %0, %0, %1, %2"
        : "+v"(b) : "v"(e0), "v"(e1));
}

__global__
__attribute__((amdgpu_flat_work_group_size(TPB, TPB)))
__attribute__((amdgpu_waves_per_eu(4, 4)))
void nn10(const float* __restrict__ src,
          const float* __restrict__ tar,
          float* __restrict__ out) {
    __shared__ float4 tile[2 * TILE];  // 64 KB double buffer; reused in tail

    const int tid   = threadIdx.x;
    const int g     = tid >> 8;     // 0..1: target half owned by this thread
    const int chunk = tid & 255;    // 0..255: source slice
    const int tbase = blockIdx.x * 32;

    // 16 targets/thread, premultiplied by -2 so ||s||^2 folds into the fmas
    float txm2[TPT], tym2[TPT], tzm2[TPT], best[TPT];
#pragma unroll
    for (int k = 0; k < TPT; ++k) {
        int T = tbase + g * TPT + k;
        txm2[k] = -2.0f * tar[3 * T + 0];
        tym2[k] = -2.0f * tar[3 * T + 1];
        tzm2[k] = -2.0f * tar[3 * T + 2];
        best[k] = INFINITY;
    }

    // ---- prolog: stage tile 0  (w = ||s||^2, exact op order matters: the
    // tail rescan replicates fmaf(x,x,fmaf(y,y,z*z)) bit-for-bit)
#pragma unroll
    for (int r = 0; r < PPT; ++r) {
        int p = tid + r * TPB;
        const float* q = src + 3 * p;
        float x = q[0], y = q[1], z = q[2];
        tile[p] = make_float4(x, y, z, fmaf(x, x, fmaf(y, y, z * z)));
    }
    __syncthreads();

    auto compute = [&](int cb) {
#pragma unroll
        for (int i = 0; i < IPT; ++i) {
            float4 s0 = tile[cb + (2 * i + 0) * CHUNKS + chunk];
            float4 s1 = tile[cb + (2 * i + 1) * CHUNKS + chunk];
#pragma unroll
            for (int k = 0; k < TPT; ++k) {
                float t0 = fmaf(s0.z, tzm2[k], s0.w);
                t0 = fmaf(s0.y, tym2[k], t0);
                t0 = fmaf(s0.x, txm2[k], t0);
                float t1 = fmaf(s1.z, tzm2[k], s1.w);
                t1 = fmaf(s1.y, tym2[k], t1);
                t1 = fmaf(s1.x, txm2[k], t1);
                min3(best[k], t0, t1);   // 7 VALU per 2 pairs = 3.5/pair
            }
        }
    };

    // ---- pipelined main loop: prefetch tl+1, compute tl, write tl+1
#pragma unroll 1
    for (int tl = 0; tl < TILES - 1; ++tl) {
        float px[PPT], py[PPT], pz[PPT];
#pragma unroll
        for (int r = 0; r < PPT; ++r) {
            const float* q = src + 3 * ((tl + 1) * TILE + tid + r * TPB);
            px[r] = q[0]; py[r] = q[1]; pz[r] = q[2];
        }
        __builtin_amdgcn_sched_barrier(0);  // keep load issues above compute

        compute((tl & 1) * TILE);

        const int wb = ((tl + 1) & 1) * TILE;
#pragma unroll
        for (int r = 0; r < PPT; ++r) {
            float x = px[r], y = py[r], z = pz[r];
            tile[wb + tid + r * TPB] =
                make_float4(x, y, z, fmaf(x, x, fmaf(y, y, z * z)));
        }
        __syncthreads();  // publishes writes for tl+1; retires reads of tl
    }
    compute(((TILES - 1) & 1) * TILE);

    // ---- tail: per-target reduce (value, chunk), then rescan winning chunk
    __syncthreads();                     // all compute reads of tile done
    float* fv = (float*)tile;            // [32][256] raw best values (32 KB)
#pragma unroll
    for (int k = 0; k < TPT; ++k) {
        fv[(g * TPT + k) * CHUNKS + chunk] = best[k];
    }
    __syncthreads();

    const int tprime = tid >> 4;   // 0..31: target this 16-lane group reduces
    const int sub    = tid & 15;
    float bv = fv[tprime * CHUNKS + sub];
    int   bc = sub;                // winning chunk id
#pragma unroll
    for (int m = 1; m < CHUNKS / 16; ++m) {
        float v = fv[tprime * CHUNKS + sub + 16 * m];
        if (v < bv) { bv = v; bc = sub + 16 * m; }
    }
#pragma unroll
    for (int s = 8; s >= 1; s >>= 1) {   // xor<16 stays in the 16-lane group
        float vv = __shfl_xor(bv, s, 64);
        int   cc = __shfl_xor(bc, s, 64);
        if (vv < bv) { bv = vv; bc = cc; }
    }
    // all 16 lanes of the group now hold (bv, bc) for target tprime.

    // ---- rescan: find the row in chunk bc whose value bit-matches bv.
    // Same fma chain as pass 1 -> the winning row reproduces bv exactly.
    const int T = tbase + tprime;
    const float tx = tar[3 * T + 0], ty = tar[3 * T + 1], tz = tar[3 * T + 2];
    const float rxm2 = -2.0f * tx, rym2 = -2.0f * ty, rzm2 = -2.0f * tz;
    int myrow = NROWS;  // sentinel
#pragma unroll
    for (int rr = 0; rr < NROWS / 16; ++rr) {
        int r = sub + 16 * rr;
        int j = r * CHUNKS + bc;
        const float* q = src + 3 * j;
        float x = q[0], y = q[1], z = q[2];
        float w = fmaf(x, x, fmaf(y, y, z * z));
        float v = fmaf(z, rzm2, w);
        v = fmaf(y, rym2, v);
        v = fmaf(x, rxm2, v);
        if (v == bv && r < myrow) myrow = r;
    }
#pragma unroll
    for (int s = 8; s >= 1; s >>= 1) {
        int r2 = __shfl_xor(myrow, s, 64);
        if (r2 < myrow) myrow = r2;
    }
    __syncthreads();  // done reading fv; safe to overwrite fv[0..31]

    if (sub == 0) {
        int j = myrow * CHUNKS + bc;
        // exact loss term from the winning index (reference formula)
        float dx = src[3 * j + 0] - tx;
        float dy = src[3 * j + 1] - ty;
        float dz = src[3 * j + 2] - tz;
        fv[tprime] = 0.5f * fmaf(dx, dx, fmaf(dy, dy, dz * dz));
    }
    __syncthreads();
    if (tid == 0) {
        float ssum = 0.0f;
#pragma unroll
        for (int i = 0; i < 32; ++i) ssum += fv[i];
        atomicAdd(out, ssum);  // device-scope, cross-XCD safe
    }
}

extern "C" void kernel_launch(void* const* d_in, const int* in_sizes, int n_in,
                              void* d_out, int out_size, void* d_ws, size_t ws_size,
                              hipStream_t stream) {
    const float* src = (const float*)d_in[0];  // src_V [N,3] fp32
    const float* tar = (const float*)d_in[1];  // tar_V [M,3] fp32
    float* out = (float*)d_out;                // scalar loss fp32
    (void)d_ws; (void)ws_size;

    zero_out<<<1, 64, 0, stream>>>(out);
    nn10<<<BLOCKS, TPB, 0, stream>>>(src, tar, out);
}

// Round 5
// 85.145 us; speedup vs baseline: 1.0404x; 1.0050x over previous
//
#include <hip/hip_runtime.h>
#include <math.h>

// Problem constants (fixed by setup_inputs): N src points, M targets, D=3.
constexpr int N_SRC = 16384;
constexpr int M_TAR = 16384;

// R10: ONE change vs R9 — target coefficients move to SGPRs.
// Diagnosis: txm2/tym2/tzm2 (48 floats) are WAVE-UNIFORM (g = tid>>8 is
// constant across each 64-lane wave), yet lived in per-lane VGPRs. With
// best[16]+operands they exceeded the allocator's stubborn 60-VGPR budget
// (stuck at 60 across 3 occupancy knobs, R7-R9), so ~35 values sat in
// AGPR/spill and every coefficient access paid a shuffle: measured VALU
// busy 25.2us vs the 12.0us instruction floor (3.5 ops/pair).
// Fix: readfirstlane each coefficient at load time -> SGPR. v_fma_f32
// reads exactly one SGPR operand per instruction (ISA limit: 1 SGPR/vec
// instr), so the inner loop keeps its exact shape:
//   per source-pair: 6 v_fma_f32 + 1 v_min3_f32 = 3.5 VALU ops/pair
// Per-lane live set drops to ~45 VGPRs — inside the cap, zero shuffles.
constexpr int BLOCKS = 512;            // 32 targets per block
constexpr int TPB = 512;               // 8 waves
constexpr int CHUNKS = 256;            // chunk = tid & 255
constexpr int TILE = 2048;             // sources per LDS tile (32 KB float4)
constexpr int TILES = N_SRC / TILE;    // 8
constexpr int ROWS_PT = TILE / CHUNKS; // 8 rows per tile
constexpr int IPT = ROWS_PT / 2;       // 4 source-pairs per tile per thread
constexpr int TPT = 16;                // targets per thread (per wave)
constexpr int PPT = TILE / TPB;        // 4 staged points per thread per tile
constexpr int NROWS = N_SRC / CHUNKS;  // 64 rows per chunk overall

__global__ void zero_out(float* __restrict__ out) {
    if (threadIdx.x == 0) out[0] = 0.0f;  // d_out poisoned 0xAA each launch
}

// best = min(best, e0, e1) in one instruction (inputs never NaN here)
__device__ __forceinline__ void min3(float& b, float e0, float e1) {
    asm("v_min3_f32 %0, %0, %1, %2"
        : "+v"(b) : "v"(e0), "v"(e1));
}

// wave-uniform float -> SGPR (bit-exact; all lanes hold the same value)
__device__ __forceinline__ float to_sgpr(float x) {
    return __uint_as_float(
        (unsigned)__builtin_amdgcn_readfirstlane((int)__float_as_uint(x)));
}

__global__
__attribute__((amdgpu_flat_work_group_size(TPB, TPB)))
__attribute__((amdgpu_waves_per_eu(4, 4)))
void nn11(const float* __restrict__ src,
          const float* __restrict__ tar,
          float* __restrict__ out) {
    __shared__ float4 tile[2 * TILE];  // 64 KB double buffer; reused in tail

    const int tid   = threadIdx.x;
    const int g     = tid >> 8;     // 0..1: wave-uniform target half
    const int chunk = tid & 255;    // 0..255: source slice
    const int tbase = blockIdx.x * 32;

    // 16 targets per WAVE (uniform across lanes) -> coefficients in SGPRs.
    // best[] is per-lane (each lane tracks the same targets over a
    // different source slice), stays VGPR.
    float txm2[TPT], tym2[TPT], tzm2[TPT], best[TPT];
#pragma unroll
    for (int k = 0; k < TPT; ++k) {
        int T = tbase + g * TPT + k;
        txm2[k] = to_sgpr(-2.0f * tar[3 * T + 0]);
        tym2[k] = to_sgpr(-2.0f * tar[3 * T + 1]);
        tzm2[k] = to_sgpr(-2.0f * tar[3 * T + 2]);
        best[k] = INFINITY;
    }

    // ---- prolog: stage tile 0  (w = ||s||^2; exact op order matters: the
    // tail rescan replicates fmaf(x,x,fmaf(y,y,z*z)) bit-for-bit)
#pragma unroll
    for (int r = 0; r < PPT; ++r) {
        int p = tid + r * TPB;
        const float* q = src + 3 * p;
        float x = q[0], y = q[1], z = q[2];
        tile[p] = make_float4(x, y, z, fmaf(x, x, fmaf(y, y, z * z)));
    }
    __syncthreads();

    auto compute = [&](int cb) {
#pragma unroll
        for (int i = 0; i < IPT; ++i) {
            float4 s0 = tile[cb + (2 * i + 0) * CHUNKS + chunk];
            float4 s1 = tile[cb + (2 * i + 1) * CHUNKS + chunk];
#pragma unroll
            for (int k = 0; k < TPT; ++k) {
                float t0 = fmaf(s0.z, tzm2[k], s0.w);   // 1 SGPR operand each
                t0 = fmaf(s0.y, tym2[k], t0);
                t0 = fmaf(s0.x, txm2[k], t0);
                float t1 = fmaf(s1.z, tzm2[k], s1.w);
                t1 = fmaf(s1.y, tym2[k], t1);
                t1 = fmaf(s1.x, txm2[k], t1);
                min3(best[k], t0, t1);   // 7 VALU per 2 pairs = 3.5/pair
            }
        }
    };

    // ---- pipelined main loop: prefetch tl+1, compute tl, write tl+1
#pragma unroll 1
    for (int tl = 0; tl < TILES - 1; ++tl) {
        float px[PPT], py[PPT], pz[PPT];
#pragma unroll
        for (int r = 0; r < PPT; ++r) {
            const float* q = src + 3 * ((tl + 1) * TILE + tid + r * TPB);
            px[r] = q[0]; py[r] = q[1]; pz[r] = q[2];
        }
        __builtin_amdgcn_sched_barrier(0);  // keep load issues above compute

        compute((tl & 1) * TILE);

        const int wb = ((tl + 1) & 1) * TILE;
#pragma unroll
        for (int r = 0; r < PPT; ++r) {
            float x = px[r], y = py[r], z = pz[r];
            tile[wb + tid + r * TPB] =
                make_float4(x, y, z, fmaf(x, x, fmaf(y, y, z * z)));
        }
        __syncthreads();  // publishes writes for tl+1; retires reads of tl
    }
    compute(((TILES - 1) & 1) * TILE);

    // ---- tail: per-target reduce (value, chunk), then rescan winning chunk
    __syncthreads();                     // all compute reads of tile done
    float* fv = (float*)tile;            // [32][256] raw best values (32 KB)
#pragma unroll
    for (int k = 0; k < TPT; ++k) {
        fv[(g * TPT + k) * CHUNKS + chunk] = best[k];
    }
    __syncthreads();

    const int tprime = tid >> 4;   // 0..31: target this 16-lane group reduces
    const int sub    = tid & 15;
    float bv = fv[tprime * CHUNKS + sub];
    int   bc = sub;                // winning chunk id
#pragma unroll
    for (int m = 1; m < CHUNKS / 16; ++m) {
        float v = fv[tprime * CHUNKS + sub + 16 * m];
        if (v < bv) { bv = v; bc = sub + 16 * m; }
    }
#pragma unroll
    for (int s = 8; s >= 1; s >>= 1) {   // xor<16 stays in the 16-lane group
        float vv = __shfl_xor(bv, s, 64);
        int   cc = __shfl_xor(bc, s, 64);
        if (vv < bv) { bv = vv; bc = cc; }
    }
    // all 16 lanes of the group now hold (bv, bc) for target tprime.

    // ---- rescan: find the row in chunk bc whose value bit-matches bv.
    // Same fma chain as pass 1 -> the winning row reproduces bv exactly.
    const int T = tbase + tprime;
    const float tx = tar[3 * T + 0], ty = tar[3 * T + 1], tz = tar[3 * T + 2];
    const float rxm2 = -2.0f * tx, rym2 = -2.0f * ty, rzm2 = -2.0f * tz;
    int myrow = NROWS;  // sentinel
#pragma unroll
    for (int rr = 0; rr < NROWS / 16; ++rr) {
        int r = sub + 16 * rr;
        int j = r * CHUNKS + bc;
        const float* q = src + 3 * j;
        float x = q[0], y = q[1], z = q[2];
        float w = fmaf(x, x, fmaf(y, y, z * z));
        float v = fmaf(z, rzm2, w);
        v = fmaf(y, rym2, v);
        v = fmaf(x, rxm2, v);
        if (v == bv && r < myrow) myrow = r;
    }
#pragma unroll
    for (int s = 8; s >= 1; s >>= 1) {
        int r2 = __shfl_xor(myrow, s, 64);
        if (r2 < myrow) myrow = r2;
    }
    __syncthreads();  // done reading fv; safe to overwrite fv[0..31]

    if (sub == 0) {
        int j = myrow * CHUNKS + bc;
        // exact loss term from the winning index (reference formula)
        float dx = src[3 * j + 0] - tx;
        float dy = src[3 * j + 1] - ty;
        float dz = src[3 * j + 2] - tz;
        fv[tprime] = 0.5f * fmaf(dx, dx, fmaf(dy, dy, dz * dz));
    }
    __syncthreads();
    if (tid == 0) {
        float ssum = 0.0f;
#pragma unroll
        for (int i = 0; i < 32; ++i) ssum += fv[i];
        atomicAdd(out, ssum);  // device-scope, cross-XCD safe
    }
}

extern "C" void kernel_launch(void* const* d_in, const int* in_sizes, int n_in,
                              void* d_out, int out_size, void* d_ws, size_t ws_size,
                              hipStream_t stream) {
    const float* src = (const float*)d_in[0];  // src_V [N,3] fp32
    const float* tar = (const float*)d_in[1];  // tar_V [M,3] fp32
    float* out = (float*)d_out;                // scalar loss fp32
    (void)d_ws; (void)ws_size;

    zero_out<<<1, 64, 0, stream>>>(out);
    nn11<<<BLOCKS, TPB, 0, stream>>>(src, tar, out);
}